// Round 7
// baseline (170.801 us; speedup 1.0000x reference)
//
#include <hip/hip_runtime.h>
#include <hip/hip_bf16.h>

#define S_LEN   2048
#define D_MODEL 1024
#define NH      16
#define DK      64
#define BATCH   2
#define M_ROWS  (BATCH * S_LEN)   // 4096
#define LDP     72                // attn Q/Ps stride (bf16 elems)
#define LDV     66                // attn Vt stride
#define LDW     132               // GEMM epilogue LDS stride

typedef __attribute__((ext_vector_type(8))) short bf16x8;
typedef __attribute__((ext_vector_type(4))) float f32x4;
typedef __attribute__((ext_vector_type(16))) float f32x16;
typedef __attribute__((ext_vector_type(8))) unsigned short us8;
typedef __attribute__((ext_vector_type(4))) unsigned short us4;

static __device__ __forceinline__ unsigned short f2bf(float f) {
    unsigned u = __builtin_bit_cast(unsigned, f);
    u += 0x7fffu + ((u >> 16) & 1u);   // RNE
    return (unsigned short)(u >> 16);
}

// ---------------------------------------------------------------------------
// All fp32->bf16 conversions in ONE launch. dst = xb | Wq | Wk | Wv | Wo.
// ---------------------------------------------------------------------------
__global__ __launch_bounds__(256) void cvt_all(const float* __restrict__ x,
                                               const float* __restrict__ wq,
                                               const float* __restrict__ wk,
                                               const float* __restrict__ wv,
                                               const float* __restrict__ wo,
                                               unsigned short* __restrict__ dst) {
    const int b = blockIdx.x;
    if (b < 2048) {
        const size_t o8 = (size_t)b * 256 + threadIdx.x;
        const float4* s = (const float4*)x + o8 * 2;
        float4 a = s[0], bb = s[1];
        us8 o;
        o[0] = f2bf(a.x);  o[1] = f2bf(a.y);  o[2] = f2bf(a.z);  o[3] = f2bf(a.w);
        o[4] = f2bf(bb.x); o[5] = f2bf(bb.y); o[6] = f2bf(bb.z); o[7] = f2bf(bb.w);
        *((us8*)dst + o8) = o;
    } else {
        const int wi = (b - 2048) >> 9;
        const float* src = (wi == 0) ? wq : (wi == 1) ? wk : (wi == 2) ? wv : wo;
        const size_t local = (size_t)((b - 2048) & 511) * 256 + threadIdx.x;
        const float4* s = (const float4*)src + local * 2;
        float4 a = s[0], bb = s[1];
        us8 o;
        o[0] = f2bf(a.x);  o[1] = f2bf(a.y);  o[2] = f2bf(a.z);  o[3] = f2bf(a.w);
        o[4] = f2bf(bb.x); o[5] = f2bf(bb.y); o[6] = f2bf(bb.z); o[7] = f2bf(bb.w);
        *((us8*)dst + 524288 + (size_t)wi * 131072 + local) = o;
    }
}

// ---------------------------------------------------------------------------
// ROUND-18: QKV GEMM, 2-wave (128-thread) blocks, per-wave 64x128 output.
// Rationale: the 2-phase structure is LDS-read-BW-bound — per kstep a 64x64
// wave does 4 ds_read_b128 (~48cyc) vs 4 MFMA 32x32x16 (~32cyc). Per-wave
// 64x128 (MI=2,NJ=4) => 6 reads / 8 MFMA = 0.75 reads/MFMA (72 vs 64 cyc).
// Unlike R2/R3's failed restructures, COVERAGE IS PRESERVED: grid stays
// 768 blocks = 3/CU exact (the proven residency), LDS 33KB x 3 = 99KB,
// 6 waves/CU (throughput-bound core; 3 independent blocks cover drains).
// Same proven staging/XOR-swizzle/fragment/epilogue patterns; + T1 remap.
// ---------------------------------------------------------------------------
__global__ __launch_bounds__(128) void gemm_qkv_w2(const unsigned short* __restrict__ A,
                                                   const unsigned short* __restrict__ W,
                                                   unsigned short* __restrict__ C) {
    constexpr int K = 1024, BM = 128, BN = 128, BK = 64;
    __shared__ unsigned short smem[128 * LDW];     // 33792B; staging uses first 32KB
    unsigned short* As = smem;                     // [128][64]
    unsigned short* Bs = smem + BM * BK;           // [128][64]

    const int tid  = threadIdx.x;
    const int w    = tid >> 6;                     // 0..1
    const int lane = tid & 63;

    // T1: XCD-aware bijective remap (nwg = 24*32 = 768, %8==0)
    const int nwg = gridDim.x * gridDim.y;
    const int lin = blockIdx.y * gridDim.x + blockIdx.x;
    const int l   = (lin & 7) * (nwg >> 3) + (lin >> 3);
    const int m0 = (l / gridDim.x) * BM;
    const int n0 = (l % gridDim.x) * BN;

    const int srow   = lane >> 3;
    const int schunk = ((lane & 7) ^ srow) * 8;
    const int l31    = lane & 31;
    const int khalf  = lane >> 5;
    const int sw     = lane & 7;
    int roff[4];
#pragma unroll
    for (int s = 0; s < 4; ++s)
        roff[s] = ((2 * s + khalf) ^ sw) * 8;

    f32x16 acc[2][4] = {};

    for (int k0 = 0; k0 < K; k0 += BK) {
        __syncthreads();
#pragma unroll
        for (int t = 0; t < 8; ++t) {              // A: 16 groups, 8/wave
            const int rbase = w * 64 + t * 8;
            const unsigned short* ga = A + (size_t)(m0 + rbase + srow) * K + k0 + schunk;
            __builtin_amdgcn_global_load_lds(
                (const __attribute__((address_space(1))) void*)ga,
                (__attribute__((address_space(3))) void*)(As + rbase * BK), 16, 0, 0);
        }
#pragma unroll
        for (int t = 0; t < 8; ++t) {              // B: 16 groups, 8/wave
            const int rbase = w * 64 + t * 8;
            const unsigned short* gb = W + (size_t)(n0 + rbase + srow) * K + k0 + schunk;
            __builtin_amdgcn_global_load_lds(
                (const __attribute__((address_space(1))) void*)gb,
                (__attribute__((address_space(3))) void*)(Bs + rbase * BK), 16, 0, 0);
        }
        __syncthreads();

#pragma unroll
        for (int s = 0; s < 4; ++s) {              // 4 ksteps of 16
            bf16x8 af[2], bfr[4];
#pragma unroll
            for (int i = 0; i < 2; ++i)
                af[i] = *(const bf16x8*)(As + (w * 64 + i * 32 + l31) * BK + roff[s]);
#pragma unroll
            for (int j = 0; j < 4; ++j)
                bfr[j] = *(const bf16x8*)(Bs + (j * 32 + l31) * BK + roff[s]);
#pragma unroll
            for (int i = 0; i < 2; ++i)
#pragma unroll
                for (int j = 0; j < 4; ++j)
                    acc[i][j] = __builtin_amdgcn_mfma_f32_32x32x16_bf16(af[i], bfr[j], acc[i][j], 0, 0, 0);
        }
    }

    // epilogue: acc -> LDS bf16 (stride LDW) -> coalesced 16B stores
    __syncthreads();
#pragma unroll
    for (int i = 0; i < 2; ++i)
#pragma unroll
        for (int j = 0; j < 4; ++j)
#pragma unroll
            for (int r = 0; r < 16; ++r) {
                const int row_l = w * 64 + i * 32 + (r & 3) + 8 * (r >> 2) + 4 * khalf;
                const int col_l = j * 32 + l31;
                smem[row_l * LDW + col_l] = f2bf(acc[i][j][r]);
            }
    __syncthreads();
#pragma unroll
    for (int e = 0; e < 16; ++e) {
        const int idx = e * 128 + tid;
        const int row = idx >> 4;
        const int cc  = (idx & 15) * 8;
        us4 lo = *(const us4*)(smem + row * LDW + cc);
        us4 hi = *(const us4*)(smem + row * LDW + cc + 4);
        us8 v;
        v[0] = lo[0]; v[1] = lo[1]; v[2] = lo[2]; v[3] = lo[3];
        v[4] = hi[0]; v[5] = hi[1]; v[6] = hi[2]; v[7] = hi[3];
        *(us8*)(C + (size_t)(m0 + row) * 3072 + n0 + cc) = v;
    }
}

// ---------------------------------------------------------------------------
// MFMA GEMM (B-transposed) + T1 swizzle — kept for the Wo projection <0,64>.
// ---------------------------------------------------------------------------
template <int STORE_BF16, int BN>
__global__ __launch_bounds__(256) void mfma_gemm_bt(const unsigned short* __restrict__ A,
                                                    const unsigned short* __restrict__ W,
                                                    void* __restrict__ Cv, int N) {
    constexpr int K = 1024, BM = 128, BK = 64;
    constexpr int MI = (BN == 128) ? 2 : 1;
    constexpr int SMEM = (STORE_BF16 && BN == 128) ? (128 * LDW)
                                                   : (BM * BK + BN * BK);
    __shared__ unsigned short smem[SMEM];
    unsigned short* As = smem;
    unsigned short* Bs = smem + BM * BK;

    const int tid  = threadIdx.x;
    const int w    = tid >> 6;
    const int lane = tid & 63;

    const int nwg = gridDim.x * gridDim.y;
    const int lin = blockIdx.y * gridDim.x + blockIdx.x;
    const int l   = (lin & 7) * (nwg >> 3) + (lin >> 3);
    const int m0 = (l / gridDim.x) * BM;
    const int n0 = (l % gridDim.x) * BN;

    const int wr = (BN == 128) ? (w >> 1) * 64 : w * 32;
    const int wc = (BN == 128) ? (w & 1) * 64 : 0;

    const int srow   = lane >> 3;
    const int schunk = ((lane & 7) ^ (lane >> 3)) * 8;
    const int l31   = lane & 31;
    const int khalf = lane >> 5;
    const int sw    = lane & 7;
    int roff[4];
#pragma unroll
    for (int s = 0; s < 4; ++s)
        roff[s] = ((2 * s + khalf) ^ sw) * 8;

    f32x16 acc[MI][2] = {};

    for (int k0 = 0; k0 < K; k0 += BK) {
        __syncthreads();
#pragma unroll
        for (int t = 0; t < 4; ++t) {
            const int rbase = w * 32 + t * 8;
            const unsigned short* ga = A + (size_t)(m0 + rbase + srow) * K + k0 + schunk;
            __builtin_amdgcn_global_load_lds(
                (const __attribute__((address_space(1))) void*)ga,
                (__attribute__((address_space(3))) void*)(As + rbase * BK), 16, 0, 0);
        }
#pragma unroll
        for (int t = 0; t < BN / 32; ++t) {
            const int rbase = w * (BN / 4) + t * 8;
            const unsigned short* gb = W + (size_t)(n0 + rbase + srow) * K + k0 + schunk;
            __builtin_amdgcn_global_load_lds(
                (const __attribute__((address_space(1))) void*)gb,
                (__attribute__((address_space(3))) void*)(Bs + rbase * BK), 16, 0, 0);
        }
        __syncthreads();

#pragma unroll
        for (int s = 0; s < 4; ++s) {
            bf16x8 af[MI], bfr[2];
#pragma unroll
            for (int i = 0; i < MI; ++i)
                af[i] = *(const bf16x8*)(As + (wr + i * 32 + l31) * BK + roff[s]);
#pragma unroll
            for (int j = 0; j < 2; ++j)
                bfr[j] = *(const bf16x8*)(Bs + (wc + j * 32 + l31) * BK + roff[s]);
#pragma unroll
            for (int i = 0; i < MI; ++i)
#pragma unroll
                for (int j = 0; j < 2; ++j)
                    acc[i][j] = __builtin_amdgcn_mfma_f32_32x32x16_bf16(af[i], bfr[j], acc[i][j], 0, 0, 0);
        }
    }

    if constexpr (STORE_BF16 && BN == 128) {
        __syncthreads();
#pragma unroll
        for (int i = 0; i < 2; ++i)
#pragma unroll
            for (int j = 0; j < 2; ++j)
#pragma unroll
                for (int r = 0; r < 16; ++r) {
                    const int row_l = wr + i * 32 + (r & 3) + 8 * (r >> 2) + 4 * khalf;
                    const int col_l = wc + j * 32 + l31;
                    smem[row_l * LDW + col_l] = f2bf(acc[i][j][r]);
                }
        __syncthreads();
#pragma unroll
        for (int e = 0; e < 8; ++e) {
            const int idx = e * 256 + tid;
            const int row = idx >> 4;
            const int cc  = (idx & 15) * 8;
            us4 lo = *(const us4*)(smem + row * LDW + cc);
            us4 hi = *(const us4*)(smem + row * LDW + cc + 4);
            us8 v;
            v[0] = lo[0]; v[1] = lo[1]; v[2] = lo[2]; v[3] = lo[3];
            v[4] = hi[0]; v[5] = hi[1]; v[6] = hi[2]; v[7] = hi[3];
            *(us8*)((unsigned short*)Cv + (size_t)(m0 + row) * N + n0 + cc) = v;
        }
    } else {
#pragma unroll
        for (int i = 0; i < MI; ++i)
#pragma unroll
            for (int j = 0; j < 2; ++j)
#pragma unroll
                for (int r = 0; r < 16; ++r) {
                    const int gm = m0 + wr + i * 32 + (r & 3) + 8 * (r >> 2) + 4 * khalf;
                    const int gn = n0 + wc + j * 32 + l31;
                    if (STORE_BF16)
                        ((unsigned short*)Cv)[(size_t)gm * N + gn] = f2bf(acc[i][j][r]);
                    else
                        ((float*)Cv)[(size_t)gm * N + gn] = acc[i][j][r];
                }
    }
}

// ---------------------------------------------------------------------------
// MFMA sliding-window ALiBi attention — ROUND-13 structure + T1 swizzle
// (the 150.7us-best configuration, frozen).
// ---------------------------------------------------------------------------
__global__ __launch_bounds__(256) void attn_mfma(const unsigned short* __restrict__ qkvb,
                                                 const float* __restrict__ slopes,
                                                 unsigned short* __restrict__ aoutb) {
    __shared__ unsigned short QPs[64 * LDP];
    __shared__ unsigned short Ks[2 * 64 * 64];
    __shared__ unsigned short Vt[64 * LDV];

    const int tid  = threadIdx.x;
    const int w    = tid >> 6;
    const int lane = tid & 63;

    const int lin = blockIdx.x + 32 * (blockIdx.y + 16 * blockIdx.z);
    const int l   = (lin & 7) * 128 + (lin >> 3);
    const int q0 = (l & 31) * 64;
    const int h  = (l >> 5) & 15;
    const int b  = l >> 9;

    const float slope = slopes[h];
    const size_t rowbase = (size_t)b * S_LEN * 3072;

#pragma unroll
    for (int e = 0; e < 2; ++e) {
        int idx = e * 256 + tid;
        int r = idx >> 3, cc = (idx & 7) * 8;
        us8 v = *(const us8*)(qkvb + rowbase + (size_t)(q0 + r) * 3072 + h * DK + cc);
        *(us8*)(QPs + r * LDP + cc) = v;
    }

    const int col = lane & 15;
    const int rq  = (lane >> 4) * 4;
    const int wq  = w * 16;
    const int fo  = (lane >> 4) * 8;

    const int srowK   = lane >> 3;
    const int schunkK = ((lane & 7) ^ srowK) * 8;
    const int kc0 = (((lane >> 4) + 0) ^ (lane & 7)) * 8;
    const int kc1 = (((lane >> 4) + 4) ^ (lane & 7)) * 8;

    const unsigned short* kbase  = qkvb + rowbase + 1024 + h * DK;
    const unsigned short* vbase0 = qkvb + rowbase + 2048 + h * DK;

    const int rp  = tid >> 3;
    const int ccv = (tid & 7) * 8;

    float qa[4];
#pragma unroll
    for (int r = 0; r < 4; ++r) {
        const int qpos = q0 + wq + rq + r;
        qa[r] = slope * (float)(qpos > 128 ? qpos - 128 : 0) - 12.0f;
    }

    f32x4 o_acc[4] = {};
    float l_part[4] = {0.f, 0.f, 0.f, 0.f};

    {
        const int k0 = q0 - 128;
#pragma unroll
        for (int t = 0; t < 2; ++t) {
            const int rbase = w * 16 + t * 8;
            const unsigned short* gk = kbase + (long long)(k0 + rbase + srowK) * 3072 + schunkK;
            __builtin_amdgcn_global_load_lds(
                (const __attribute__((address_space(1))) void*)gk,
                (__attribute__((address_space(3))) void*)(Ks + rbase * 64), 16, 0, 0);
        }
        const long long kp0 = (long long)(k0 + rp * 2);
        us8 v0 = *(const us8*)(vbase0 + ccv + kp0 * 3072);
        us8 v1 = *(const us8*)(vbase0 + ccv + (kp0 + 1) * 3072);
#pragma unroll
        for (int t = 0; t < 8; ++t) {
            unsigned pk = (unsigned)(unsigned short)v0[t] | ((unsigned)(unsigned short)v1[t] << 16);
            *(unsigned*)(Vt + (ccv + t) * LDV + rp * 2) = pk;
        }
    }
    __syncthreads();

    const bf16x8 aq0 = *(const bf16x8*)(QPs + (wq + col) * LDP + fo);
    const bf16x8 aq1 = *(const bf16x8*)(QPs + (wq + col) * LDP + fo + 32);

    int cur = 0;
    for (int c = 0; c < 5; ++c) {
        const int k0 = q0 - 128 + c * 64;
        const unsigned short* KsC = Ks + cur * 4096;
        const bool have_next = (c < 4);

        us8 nv0, nv1;
        if (have_next) {
            const int kn0 = k0 + 64;
            unsigned short* KsN = (unsigned short*)Ks + (cur ^ 1) * 4096;
#pragma unroll
            for (int t = 0; t < 2; ++t) {
                const int rbase = w * 16 + t * 8;
                const unsigned short* gk = kbase + (long long)(kn0 + rbase + srowK) * 3072 + schunkK;
                __builtin_amdgcn_global_load_lds(
                    (const __attribute__((address_space(1))) void*)gk,
                    (__attribute__((address_space(3))) void*)(KsN + rbase * 64), 16, 0, 0);
            }
            const long long kp0 = (long long)(kn0 + rp * 2);
            nv0 = *(const us8*)(vbase0 + ccv + kp0 * 3072);
            nv1 = *(const us8*)(vbase0 + ccv + (kp0 + 1) * 3072);
        }

        f32x4 sacc[4] = {};
        __builtin_amdgcn_s_setprio(1);
#pragma unroll
        for (int j = 0; j < 4; ++j) {
            const int tt  = wq - 64 * c - 16 * j;
            const int klo = k0 + 16 * j;
            const bool any_v = (tt <= 0) && (tt >= -256) && (klo < S_LEN) && (klo + 15 >= 0);
            if (any_v) {
                bf16x8 bk0 = *(const bf16x8*)(KsC + (j * 16 + col) * 64 + kc0);
                bf16x8 bk1 = *(const bf16x8*)(KsC + (j * 16 + col) * 64 + kc1);
                sacc[j] = __builtin_amdgcn_mfma_f32_16x16x32_bf16(aq0, bk0, sacc[j], 0, 0, 0);
                sacc[j] = __builtin_amdgcn_mfma_f32_16x16x32_bf16(aq1, bk1, sacc[j], 0, 0, 0);
            }
        }
        __builtin_amdgcn_s_setprio(0);

#pragma unroll
        for (int j = 0; j < 4; ++j) {
            const int tt  = wq - 64 * c - 16 * j;
            const int klo = k0 + 16 * j;
            const bool any_v = (tt <= 0) && (tt >= -256) && (klo < S_LEN) && (klo + 15 >= 0);
            unsigned short* ps = QPs + (wq + rq) * LDP + j * 16 + col;
            if (!any_v) {
#pragma unroll
                for (int r = 0; r < 4; ++r) ps[r * LDP] = 0;
            } else {
                const float kb = slope * (float)(klo + col);
                const bool all_v = (tt <= -16) && (tt >= -240) && (klo >= 0) && (klo + 15 < S_LEN);
                if (all_v) {
#pragma unroll
                    for (int r = 0; r < 4; ++r) {
                        float p = __expf(fmaf(sacc[j][r], 0.125f, qa[r] - kb));
                        l_part[r] += p;
                        ps[r * LDP] = f2bf(p);
                    }
                } else {
                    const int kpos = klo + col;
                    const bool kin = (unsigned)kpos < (unsigned)S_LEN;
#pragma unroll
                    for (int r = 0; r < 4; ++r) {
                        const int rel = (q0 + wq + rq + r) - kpos;
                        const bool ok = kin && (rel <= 128) && (rel >= -128);
                        float p = 0.f;
                        if (ok) p = __expf(fmaf(sacc[j][r], 0.125f, qa[r] - kb));
                        l_part[r] += p;
                        ps[r * LDP] = f2bf(p);
                    }
                }
            }
        }

        {
            bf16x8 ap0 = *(const bf16x8*)(QPs + (wq + col) * LDP + fo);
            bf16x8 ap1 = *(const bf16x8*)(QPs + (wq + col) * LDP + fo + 32);
            __builtin_amdgcn_s_setprio(1);
#pragma unroll
            for (int j = 0; j < 4; ++j) {
                bf16x8 bv0 = *(const bf16x8*)(Vt + (j * 16 + col) * LDV + fo);
                bf16x8 bv1 = *(const bf16x8*)(Vt + (j * 16 + col) * LDV + fo + 32);
                o_acc[j] = __builtin_amdgcn_mfma_f32_16x16x32_bf16(ap0, bv0, o_acc[j], 0, 0, 0);
                o_acc[j] = __builtin_amdgcn_mfma_f32_16x16x32_bf16(ap1, bv1, o_acc[j], 0, 0, 0);
            }
            __builtin_amdgcn_s_setprio(0);
        }

        if (have_next) {
            __syncthreads();
#pragma unroll
            for (int t = 0; t < 8; ++t) {
                unsigned pk = (unsigned)(unsigned short)nv0[t] | ((unsigned)(unsigned short)nv1[t] << 16);
                *(unsigned*)(Vt + (ccv + t) * LDV + rp * 2) = pk;
            }
            __syncthreads();
        }
        cur ^= 1;
    }

    float inv[4];
#pragma unroll
    for (int r = 0; r < 4; ++r) {
        float l2 = l_part[r];
#pragma unroll
        for (int off = 1; off < 16; off <<= 1) l2 += __shfl_xor(l2, off, 64);
        inv[r] = 1.f / l2;
    }

#pragma unroll
    for (int j = 0; j < 4; ++j)
#pragma unroll
        for (int r = 0; r < 4; ++r) {
            const int qpos = q0 + wq + rq + r;
            aoutb[((size_t)b * S_LEN + qpos) * D_MODEL + h * DK + j * 16 + col] =
                f2bf(o_acc[j][r] * inv[r]);
        }
}

// ---------------------------------------------------------------------------
extern "C" void kernel_launch(void* const* d_in, const int* in_sizes, int n_in,
                              void* d_out, int out_size, void* d_ws, size_t ws_size,
                              hipStream_t stream) {
    const float* x      = (const float*)d_in[0];
    const float* Wq     = (const float*)d_in[1];
    const float* Wk     = (const float*)d_in[2];
    const float* Wv     = (const float*)d_in[3];
    const float* Wo     = (const float*)d_in[4];
    const float* slopes = (const float*)d_in[5];
    float* out = (float*)d_out;

    unsigned short* xb    = (unsigned short*)d_ws;            // [4096,1024]
    unsigned short* wb    = xb    + (size_t)M_ROWS * D_MODEL; // [3072,1024] Wq|Wk|Wv
    unsigned short* wob   = wb    + (size_t)3072 * D_MODEL;   // [1024,1024]
    unsigned short* qkvb  = wob   + (size_t)1024 * D_MODEL;   // [4096,3072]
    unsigned short* aoutb = qkvb  + (size_t)M_ROWS * 3072;    // [4096,1024]

    dim3 blk(256);
    cvt_all<<<4096, blk, 0, stream>>>(x, Wq, Wk, Wv, Wo, xb);
    gemm_qkv_w2<<<dim3(3072 / 128, M_ROWS / 128), dim3(128), 0, stream>>>(xb, wb, qkvb);
    attn_mfma<<<dim3(S_LEN / 64, NH, BATCH), blk, 0, stream>>>(qkvb, slopes, aoutb);
    mfma_gemm_bt<0, 64><<<dim3(1024 / 64, M_ROWS / 128), blk, 0, stream>>>(aoutb, wob, out, 1024);
}

// Round 8
// 150.330 us; speedup vs baseline: 1.1362x; 1.1362x over previous
//
#include <hip/hip_runtime.h>
#include <hip/hip_bf16.h>

#define S_LEN   2048
#define D_MODEL 1024
#define NH      16
#define DK      64
#define BATCH   2
#define M_ROWS  (BATCH * S_LEN)   // 4096
#define LDP     72                // attn Q/Ps stride (bf16 elems)
#define LDV     66                // attn Vt stride
#define LDW     132               // GEMM epilogue LDS stride

typedef __attribute__((ext_vector_type(8))) short bf16x8;
typedef __attribute__((ext_vector_type(4))) float f32x4;
typedef __attribute__((ext_vector_type(16))) float f32x16;
typedef __attribute__((ext_vector_type(8))) unsigned short us8;
typedef __attribute__((ext_vector_type(4))) unsigned short us4;

static __device__ __forceinline__ unsigned short f2bf(float f) {
    unsigned u = __builtin_bit_cast(unsigned, f);
    u += 0x7fffu + ((u >> 16) & 1u);   // RNE
    return (unsigned short)(u >> 16);
}

// ---------------------------------------------------------------------------
// All fp32->bf16 conversions in ONE launch. dst = xb | Wq | Wk | Wv | Wo.
// (no XCD swizzle: streaming, zero inter-block reuse — T1 null per m219)
// ---------------------------------------------------------------------------
__global__ __launch_bounds__(256) void cvt_all(const float* __restrict__ x,
                                               const float* __restrict__ wq,
                                               const float* __restrict__ wk,
                                               const float* __restrict__ wv,
                                               const float* __restrict__ wo,
                                               unsigned short* __restrict__ dst) {
    const int b = blockIdx.x;
    if (b < 2048) {
        const size_t o8 = (size_t)b * 256 + threadIdx.x;
        const float4* s = (const float4*)x + o8 * 2;
        float4 a = s[0], bb = s[1];
        us8 o;
        o[0] = f2bf(a.x);  o[1] = f2bf(a.y);  o[2] = f2bf(a.z);  o[3] = f2bf(a.w);
        o[4] = f2bf(bb.x); o[5] = f2bf(bb.y); o[6] = f2bf(bb.z); o[7] = f2bf(bb.w);
        *((us8*)dst + o8) = o;
    } else {
        const int wi = (b - 2048) >> 9;
        const float* src = (wi == 0) ? wq : (wi == 1) ? wk : (wi == 2) ? wv : wo;
        const size_t local = (size_t)((b - 2048) & 511) * 256 + threadIdx.x;
        const float4* s = (const float4*)src + local * 2;
        float4 a = s[0], bb = s[1];
        us8 o;
        o[0] = f2bf(a.x);  o[1] = f2bf(a.y);  o[2] = f2bf(a.z);  o[3] = f2bf(a.w);
        o[4] = f2bf(bb.x); o[5] = f2bf(bb.y); o[6] = f2bf(bb.z); o[7] = f2bf(bb.w);
        *((us8*)dst + 524288 + (size_t)wi * 131072 + local) = o;
    }
}

// ---------------------------------------------------------------------------
// MFMA GEMM (B-transposed): C[m,n] = sum_k A[m,k]*W[n,k], bf16 in, K=1024.
// ROUND-19: exact revert to the measured-best (150.7us) round-17 version.
// T1 XCD-aware bijective block swizzle on top of the proven 2-phase 128-tile
// structure. R6 post-mortem (gemm_qkv_w2: Occ 7.3%, MfmaUtil 17%) confirmed
// TLP (12 waves/CU here) dominates per-wave read-ratio at this problem size;
// the 32-row x 16B fragment read is the structural LDS BW floor (512B = 4
// bank-cycles), not a fixable conflict. This structure is the envelope.
// ---------------------------------------------------------------------------
template <int STORE_BF16, int BN>
__global__ __launch_bounds__(256) void mfma_gemm_bt(const unsigned short* __restrict__ A,
                                                    const unsigned short* __restrict__ W,
                                                    void* __restrict__ Cv, int N) {
    constexpr int K = 1024, BM = 128, BK = 64;
    constexpr int MI = (BN == 128) ? 2 : 1;              // 32-row m-frags per wave
    constexpr int SMEM = (STORE_BF16 && BN == 128) ? (128 * LDW)
                                                   : (BM * BK + BN * BK);
    __shared__ unsigned short smem[SMEM];
    unsigned short* As = smem;               // [BM][BK]
    unsigned short* Bs = smem + BM * BK;     // [BN][BK]

    const int tid  = threadIdx.x;
    const int w    = tid >> 6;
    const int lane = tid & 63;

    // T1: XCD-aware bijective remap
    const int nwg = gridDim.x * gridDim.y;
    const int lin = blockIdx.y * gridDim.x + blockIdx.x;
    const int l   = (lin & 7) * (nwg >> 3) + (lin >> 3);
    const int m0 = (l / gridDim.x) * BM;
    const int n0 = (l % gridDim.x) * BN;

    const int wr = (BN == 128) ? (w >> 1) * 64 : w * 32;
    const int wc = (BN == 128) ? (w & 1) * 64 : 0;

    const int srow   = lane >> 3;                          // 0..7
    const int schunk = ((lane & 7) ^ (lane >> 3)) * 8;     // swizzled k-chunk (elems)
    const int l31   = lane & 31;
    const int khalf = lane >> 5;                           // 0/1
    const int sw    = lane & 7;
    int roff[4];
#pragma unroll
    for (int s = 0; s < 4; ++s)
        roff[s] = ((2 * s + khalf) ^ sw) * 8;              // kstep s read offset

    f32x16 acc[MI][2] = {};

    for (int k0 = 0; k0 < K; k0 += BK) {
        __syncthreads();
#pragma unroll
        for (int t = 0; t < 4; ++t) {                      // A: 16 groups, 4/wave
            const int rbase = w * 32 + t * 8;
            const unsigned short* ga = A + (size_t)(m0 + rbase + srow) * K + k0 + schunk;
            __builtin_amdgcn_global_load_lds(
                (const __attribute__((address_space(1))) void*)ga,
                (__attribute__((address_space(3))) void*)(As + rbase * BK), 16, 0, 0);
        }
#pragma unroll
        for (int t = 0; t < BN / 32; ++t) {                // B: wave stride BN/4
            const int rbase = w * (BN / 4) + t * 8;
            const unsigned short* gb = W + (size_t)(n0 + rbase + srow) * K + k0 + schunk;
            __builtin_amdgcn_global_load_lds(
                (const __attribute__((address_space(1))) void*)gb,
                (__attribute__((address_space(3))) void*)(Bs + rbase * BK), 16, 0, 0);
        }
        __syncthreads();

#pragma unroll
        for (int s = 0; s < 4; ++s) {                      // 4 ksteps of 16
            bf16x8 af[MI], bfr[2];
#pragma unroll
            for (int i = 0; i < MI; ++i)
                af[i] = *(const bf16x8*)(As + (wr + i * 32 + l31) * BK + roff[s]);
#pragma unroll
            for (int j = 0; j < 2; ++j)
                bfr[j] = *(const bf16x8*)(Bs + (wc + j * 32 + l31) * BK + roff[s]);
#pragma unroll
            for (int i = 0; i < MI; ++i)
#pragma unroll
                for (int j = 0; j < 2; ++j)
                    acc[i][j] = __builtin_amdgcn_mfma_f32_32x32x16_bf16(af[i], bfr[j], acc[i][j], 0, 0, 0);
        }
    }

    if constexpr (STORE_BF16 && BN == 128) {
        // C -> LDS (stride LDW) -> coalesced 16B stores.
        __syncthreads();
#pragma unroll
        for (int i = 0; i < 2; ++i)
#pragma unroll
            for (int j = 0; j < 2; ++j)
#pragma unroll
                for (int r = 0; r < 16; ++r) {
                    const int row_l = wr + i * 32 + (r & 3) + 8 * (r >> 2) + 4 * khalf;
                    const int col_l = wc + j * 32 + l31;
                    smem[row_l * LDW + col_l] = f2bf(acc[i][j][r]);
                }
        __syncthreads();
#pragma unroll
        for (int e = 0; e < 8; ++e) {
            const int idx = e * 256 + tid;
            const int row = idx >> 4;
            const int cc  = (idx & 15) * 8;
            us4 lo = *(const us4*)(smem + row * LDW + cc);
            us4 hi = *(const us4*)(smem + row * LDW + cc + 4);
            us8 v;
            v[0] = lo[0]; v[1] = lo[1]; v[2] = lo[2]; v[3] = lo[3];
            v[4] = hi[0]; v[5] = hi[1]; v[6] = hi[2]; v[7] = hi[3];
            *(us8*)((unsigned short*)Cv + (size_t)(m0 + row) * N + n0 + cc) = v;
        }
    } else {
#pragma unroll
        for (int i = 0; i < MI; ++i)
#pragma unroll
            for (int j = 0; j < 2; ++j)
#pragma unroll
                for (int r = 0; r < 16; ++r) {
                    const int gm = m0 + wr + i * 32 + (r & 3) + 8 * (r >> 2) + 4 * khalf;
                    const int gn = n0 + wc + j * 32 + l31;
                    if (STORE_BF16)
                        ((unsigned short*)Cv)[(size_t)gm * N + gn] = f2bf(acc[i][j][r]);
                    else
                        ((float*)Cv)[(size_t)gm * N + gn] = acc[i][j][r];
                }
    }
}

// ---------------------------------------------------------------------------
// MFMA sliding-window ALiBi attention — ROUND-13 structure + T1 swizzle
// (the 150.7us-best configuration, frozen).
// ---------------------------------------------------------------------------
__global__ __launch_bounds__(256) void attn_mfma(const unsigned short* __restrict__ qkvb,
                                                 const float* __restrict__ slopes,
                                                 unsigned short* __restrict__ aoutb) {
    __shared__ unsigned short QPs[64 * LDP];
    __shared__ unsigned short Ks[2 * 64 * 64];
    __shared__ unsigned short Vt[64 * LDV];

    const int tid  = threadIdx.x;
    const int w    = tid >> 6;
    const int lane = tid & 63;

    // T1: XCD-aware bijective remap of (q-tile, head, batch)
    const int lin = blockIdx.x + 32 * (blockIdx.y + 16 * blockIdx.z);
    const int l   = (lin & 7) * 128 + (lin >> 3);
    const int q0 = (l & 31) * 64;
    const int h  = (l >> 5) & 15;
    const int b  = l >> 9;

    const float slope = slopes[h];
    const size_t rowbase = (size_t)b * S_LEN * 3072;

#pragma unroll
    for (int e = 0; e < 2; ++e) {
        int idx = e * 256 + tid;
        int r = idx >> 3, cc = (idx & 7) * 8;
        us8 v = *(const us8*)(qkvb + rowbase + (size_t)(q0 + r) * 3072 + h * DK + cc);
        *(us8*)(QPs + r * LDP + cc) = v;
    }

    const int col = lane & 15;
    const int rq  = (lane >> 4) * 4;
    const int wq  = w * 16;
    const int fo  = (lane >> 4) * 8;

    const int srowK   = lane >> 3;
    const int schunkK = ((lane & 7) ^ srowK) * 8;
    const int kc0 = (((lane >> 4) + 0) ^ (lane & 7)) * 8;
    const int kc1 = (((lane >> 4) + 4) ^ (lane & 7)) * 8;

    const unsigned short* kbase  = qkvb + rowbase + 1024 + h * DK;
    const unsigned short* vbase0 = qkvb + rowbase + 2048 + h * DK;

    const int rp  = tid >> 3;
    const int ccv = (tid & 7) * 8;

    float qa[4];
#pragma unroll
    for (int r = 0; r < 4; ++r) {
        const int qpos = q0 + wq + rq + r;
        qa[r] = slope * (float)(qpos > 128 ? qpos - 128 : 0) - 12.0f;
    }

    f32x4 o_acc[4] = {};
    float l_part[4] = {0.f, 0.f, 0.f, 0.f};

    {
        const int k0 = q0 - 128;
#pragma unroll
        for (int t = 0; t < 2; ++t) {
            const int rbase = w * 16 + t * 8;
            const unsigned short* gk = kbase + (long long)(k0 + rbase + srowK) * 3072 + schunkK;
            __builtin_amdgcn_global_load_lds(
                (const __attribute__((address_space(1))) void*)gk,
                (__attribute__((address_space(3))) void*)(Ks + rbase * 64), 16, 0, 0);
        }
        const long long kp0 = (long long)(k0 + rp * 2);
        us8 v0 = *(const us8*)(vbase0 + ccv + kp0 * 3072);
        us8 v1 = *(const us8*)(vbase0 + ccv + (kp0 + 1) * 3072);
#pragma unroll
        for (int t = 0; t < 8; ++t) {
            unsigned pk = (unsigned)(unsigned short)v0[t] | ((unsigned)(unsigned short)v1[t] << 16);
            *(unsigned*)(Vt + (ccv + t) * LDV + rp * 2) = pk;
        }
    }
    __syncthreads();

    const bf16x8 aq0 = *(const bf16x8*)(QPs + (wq + col) * LDP + fo);
    const bf16x8 aq1 = *(const bf16x8*)(QPs + (wq + col) * LDP + fo + 32);

    int cur = 0;
    for (int c = 0; c < 5; ++c) {
        const int k0 = q0 - 128 + c * 64;
        const unsigned short* KsC = Ks + cur * 4096;
        const bool have_next = (c < 4);

        us8 nv0, nv1;
        if (have_next) {
            const int kn0 = k0 + 64;
            unsigned short* KsN = (unsigned short*)Ks + (cur ^ 1) * 4096;
#pragma unroll
            for (int t = 0; t < 2; ++t) {
                const int rbase = w * 16 + t * 8;
                const unsigned short* gk = kbase + (long long)(kn0 + rbase + srowK) * 3072 + schunkK;
                __builtin_amdgcn_global_load_lds(
                    (const __attribute__((address_space(1))) void*)gk,
                    (__attribute__((address_space(3))) void*)(KsN + rbase * 64), 16, 0, 0);
            }
            const long long kp0 = (long long)(kn0 + rp * 2);
            nv0 = *(const us8*)(vbase0 + ccv + kp0 * 3072);
            nv1 = *(const us8*)(vbase0 + ccv + (kp0 + 1) * 3072);
        }

        f32x4 sacc[4] = {};
        __builtin_amdgcn_s_setprio(1);
#pragma unroll
        for (int j = 0; j < 4; ++j) {
            const int tt  = wq - 64 * c - 16 * j;
            const int klo = k0 + 16 * j;
            const bool any_v = (tt <= 0) && (tt >= -256) && (klo < S_LEN) && (klo + 15 >= 0);
            if (any_v) {
                bf16x8 bk0 = *(const bf16x8*)(KsC + (j * 16 + col) * 64 + kc0);
                bf16x8 bk1 = *(const bf16x8*)(KsC + (j * 16 + col) * 64 + kc1);
                sacc[j] = __builtin_amdgcn_mfma_f32_16x16x32_bf16(aq0, bk0, sacc[j], 0, 0, 0);
                sacc[j] = __builtin_amdgcn_mfma_f32_16x16x32_bf16(aq1, bk1, sacc[j], 0, 0, 0);
            }
        }
        __builtin_amdgcn_s_setprio(0);

#pragma unroll
        for (int j = 0; j < 4; ++j) {
            const int tt  = wq - 64 * c - 16 * j;
            const int klo = k0 + 16 * j;
            const bool any_v = (tt <= 0) && (tt >= -256) && (klo < S_LEN) && (klo + 15 >= 0);
            unsigned short* ps = QPs + (wq + rq) * LDP + j * 16 + col;
            if (!any_v) {
#pragma unroll
                for (int r = 0; r < 4; ++r) ps[r * LDP] = 0;
            } else {
                const float kb = slope * (float)(klo + col);
                const bool all_v = (tt <= -16) && (tt >= -240) && (klo >= 0) && (klo + 15 < S_LEN);
                if (all_v) {
#pragma unroll
                    for (int r = 0; r < 4; ++r) {
                        float p = __expf(fmaf(sacc[j][r], 0.125f, qa[r] - kb));
                        l_part[r] += p;
                        ps[r * LDP] = f2bf(p);
                    }
                } else {
                    const int kpos = klo + col;
                    const bool kin = (unsigned)kpos < (unsigned)S_LEN;
#pragma unroll
                    for (int r = 0; r < 4; ++r) {
                        const int rel = (q0 + wq + rq + r) - kpos;
                        const bool ok = kin && (rel <= 128) && (rel >= -128);
                        float p = 0.f;
                        if (ok) p = __expf(fmaf(sacc[j][r], 0.125f, qa[r] - kb));
                        l_part[r] += p;
                        ps[r * LDP] = f2bf(p);
                    }
                }
            }
        }

        {
            bf16x8 ap0 = *(const bf16x8*)(QPs + (wq + col) * LDP + fo);
            bf16x8 ap1 = *(const bf16x8*)(QPs + (wq + col) * LDP + fo + 32);
            __builtin_amdgcn_s_setprio(1);
#pragma unroll
            for (int j = 0; j < 4; ++j) {
                bf16x8 bv0 = *(const bf16x8*)(Vt + (j * 16 + col) * LDV + fo);
                bf16x8 bv1 = *(const bf16x8*)(Vt + (j * 16 + col) * LDV + fo + 32);
                o_acc[j] = __builtin_amdgcn_mfma_f32_16x16x32_bf16(ap0, bv0, o_acc[j], 0, 0, 0);
                o_acc[j] = __builtin_amdgcn_mfma_f32_16x16x32_bf16(ap1, bv1, o_acc[j], 0, 0, 0);
            }
            __builtin_amdgcn_s_setprio(0);
        }

        if (have_next) {
            __syncthreads();
#pragma unroll
            for (int t = 0; t < 8; ++t) {
                unsigned pk = (unsigned)(unsigned short)nv0[t] | ((unsigned)(unsigned short)nv1[t] << 16);
                *(unsigned*)(Vt + (ccv + t) * LDV + rp * 2) = pk;
            }
            __syncthreads();
        }
        cur ^= 1;
    }

    float inv[4];
#pragma unroll
    for (int r = 0; r < 4; ++r) {
        float l2 = l_part[r];
#pragma unroll
        for (int off = 1; off < 16; off <<= 1) l2 += __shfl_xor(l2, off, 64);
        inv[r] = 1.f / l2;
    }

#pragma unroll
    for (int j = 0; j < 4; ++j)
#pragma unroll
        for (int r = 0; r < 4; ++r) {
            const int qpos = q0 + wq + rq + r;
            aoutb[((size_t)b * S_LEN + qpos) * D_MODEL + h * DK + j * 16 + col] =
                f2bf(o_acc[j][r] * inv[r]);
        }
}

// ---------------------------------------------------------------------------
extern "C" void kernel_launch(void* const* d_in, const int* in_sizes, int n_in,
                              void* d_out, int out_size, void* d_ws, size_t ws_size,
                              hipStream_t stream) {
    const float* x      = (const float*)d_in[0];
    const float* Wq     = (const float*)d_in[1];
    const float* Wk     = (const float*)d_in[2];
    const float* Wv     = (const float*)d_in[3];
    const float* Wo     = (const float*)d_in[4];
    const float* slopes = (const float*)d_in[5];
    float* out = (float*)d_out;

    unsigned short* xb    = (unsigned short*)d_ws;            // [4096,1024]
    unsigned short* wb    = xb    + (size_t)M_ROWS * D_MODEL; // [3072,1024] Wq|Wk|Wv
    unsigned short* wob   = wb    + (size_t)3072 * D_MODEL;   // [1024,1024]
    unsigned short* qkvb  = wob   + (size_t)1024 * D_MODEL;   // [4096,3072]
    unsigned short* aoutb = qkvb  + (size_t)M_ROWS * 3072;    // [4096,1024]

    dim3 blk(256);
    cvt_all<<<4096, blk, 0, stream>>>(x, Wq, Wk, Wv, Wo, xb);
    mfma_gemm_bt<1, 128><<<dim3(3072 / 128, M_ROWS / 128), blk, 0, stream>>>(xb, wb, qkvb, 3072);
    attn_mfma<<<dim3(S_LEN / 64, NH, BATCH), blk, 0, stream>>>(qkvb, slopes, aoutb);
    mfma_gemm_bt<0, 64><<<dim3(1024 / 64, M_ROWS / 128), blk, 0, stream>>>(aoutb, wob, out, 1024);
}